// Round 9
// baseline (787.895 us; speedup 1.0000x reference)
//
#include <hip/hip_runtime.h>
#include <hip/hip_fp16.h>

#define CDIM 64
#define COARSE_SHIFT 10          // 1024 rows per coarse bucket
#define CHUNK 8192
#define MAXB 256                 // >= max coarse buckets (200000>>10 = 196)

// ---- fp16 pack/unpack helpers ----
__device__ __forceinline__ ushort4 f4h(float4 v) {
    ushort4 h;
    h.x = __half_as_ushort(__float2half_rn(v.x));
    h.y = __half_as_ushort(__float2half_rn(v.y));
    h.z = __half_as_ushort(__float2half_rn(v.z));
    h.w = __half_as_ushort(__float2half_rn(v.w));
    return h;
}

// 4 halves = 2 packed half2 (8B). Row = 128B = 16 HPack.
struct alignas(8) HPack { __half2 lo, hi; };

__device__ __forceinline__ HPack f4hp(float4 v) {
    HPack p; p.lo = __floats2half2_rn(v.x, v.y); p.hi = __floats2half2_rn(v.z, v.w);
    return p;
}
__device__ __forceinline__ float4 hp2f4(__half2 lo, __half2 hi) {
    return make_float4(__low2float(lo), __high2float(lo),
                       __low2float(hi), __high2float(hi));
}

// ---------------- init: residual slots of d_out + fp16 hop-state seed ----------------
__global__ void init_kernel(const float4* __restrict__ user_emb,
                            const float4* __restrict__ ent_emb,
                            float4* __restrict__ outUserRes,
                            float4* __restrict__ outNodeRes,
                            ushort4* __restrict__ uH,
                            ushort4* __restrict__ entH,
                            long nuC4, long neC4) {
    long i = (long)blockIdx.x * blockDim.x + threadIdx.x;
    if (i < nuC4) {
        float4 v = user_emb[i];
        outUserRes[i] = v; outNodeRes[i] = v; uH[i] = f4h(v);
    }
    if (i < neC4) {
        float4 v = ent_emb[i];
        outNodeRes[nuC4 + i] = v; entH[i] = f4h(v);
    }
}

// ---------------- coarse histogram (LDS-staged) ----------------
__global__ void hist_coarse(const int* __restrict__ dst, int n,
                            int* __restrict__ cnt, int Bc) {
    __shared__ int h[MAXB];
    for (int i = threadIdx.x; i < MAXB; i += blockDim.x) h[i] = 0;
    __syncthreads();
    int stride = gridDim.x * blockDim.x;
    for (int e = blockIdx.x * blockDim.x + threadIdx.x; e < n; e += stride)
        atomicAdd(&h[dst[e] >> COARSE_SHIFT], 1);
    __syncthreads();
    for (int b = threadIdx.x; b < Bc; b += blockDim.x)
        if (h[b]) atomicAdd(&cnt[b], h[b]);
}

// ---------------- small exclusive scan (single WG, n<=256) ----------------
__global__ void scan_small(const int* __restrict__ cnt, int* __restrict__ start,
                           int* __restrict__ cursor, int n) {
    __shared__ int tmp[256];
    int x = threadIdx.x;
    int v = (x < n) ? cnt[x] : 0;
    tmp[x] = v; __syncthreads();
    for (int off = 1; off < 256; off <<= 1) {
        int t = (x >= off) ? tmp[x - off] : 0;
        __syncthreads();
        tmp[x] += t;
        __syncthreads();
    }
    if (x < n) { start[x] = tmp[x] - v; cursor[x] = tmp[x] - v; }
    if (x == n - 1) start[n] = tmp[x];
}

// ---------------- coarse binning, LDS-staged segment writes ----------------
// key = rowlocal<<22 | typ<<18 | src   (rowlocal<1024, typ<16, src<2^18)
__global__ void bin_pairs(const int* __restrict__ dst, const int* __restrict__ src,
                          const int* __restrict__ typ, int typeBias, int n,
                          int* __restrict__ cursor, int* __restrict__ stage) {
    __shared__ int h[MAXB];
    __shared__ int base[MAXB];
    int cs = blockIdx.x * CHUNK;
    int ce = min(cs + CHUNK, n);
    for (int i = threadIdx.x; i < MAXB; i += blockDim.x) h[i] = 0;
    __syncthreads();
    for (int e = cs + threadIdx.x; e < ce; e += blockDim.x)
        atomicAdd(&h[dst[e] >> COARSE_SHIFT], 1);
    __syncthreads();
    for (int b = threadIdx.x; b < MAXB; b += blockDim.x) {
        int c = h[b];
        base[b] = c ? atomicAdd(&cursor[b], c) : 0;
        h[b] = 0;
    }
    __syncthreads();
    for (int e = cs + threadIdx.x; e < ce; e += blockDim.x) {
        int d = dst[e];
        int b = d >> COARSE_SHIFT;
        int off = atomicAdd(&h[b], 1);
        stage[base[b] + off] = ((d & 1023) << 22) | ((typ[e] + typeBias) << 18) | src[e];
    }
}

// user variant: key = rowlocal<<22 | col (col<2^22), parallel val array
__global__ void bin_user(const int* __restrict__ row, const int* __restrict__ col,
                         const float* __restrict__ val, int n,
                         int* __restrict__ cursor,
                         int* __restrict__ stage, float* __restrict__ stageVal) {
    __shared__ int h[MAXB];
    __shared__ int base[MAXB];
    int cs = blockIdx.x * CHUNK;
    int ce = min(cs + CHUNK, n);
    for (int i = threadIdx.x; i < MAXB; i += blockDim.x) h[i] = 0;
    __syncthreads();
    for (int e = cs + threadIdx.x; e < ce; e += blockDim.x)
        atomicAdd(&h[row[e] >> COARSE_SHIFT], 1);
    __syncthreads();
    for (int b = threadIdx.x; b < MAXB; b += blockDim.x) {
        int c = h[b];
        base[b] = c ? atomicAdd(&cursor[b], c) : 0;
        h[b] = 0;
    }
    __syncthreads();
    for (int e = cs + threadIdx.x; e < ce; e += blockDim.x) {
        int d = row[e];
        int b = d >> COARSE_SHIFT;
        int off = atomicAdd(&h[b], 1);
        int pos = base[b] + off;
        stage[pos] = ((d & 1023) << 22) | col[e];
        stageVal[pos] = val[e];
    }
}

// ---------------- full per-row sort within coarse bucket (L2-resident) ----------------
__global__ void __launch_bounds__(256)
subsort(const int* __restrict__ coarseStart,
        const int* __restrict__ stage, const float* __restrict__ stageVal,
        int* __restrict__ bin, float* __restrict__ binVal,
        int* __restrict__ rowStart, int Bc, int N, int total) {
    __shared__ int h[1024];
    __shared__ int base[1024];
    __shared__ int sarr[256];
    int c = blockIdx.x;
    int s = coarseStart[c], e = coarseStart[c + 1];
    for (int i = threadIdx.x; i < 1024; i += 256) h[i] = 0;
    __syncthreads();
    for (int j = s + threadIdx.x; j < e; j += 256)
        atomicAdd(&h[(stage[j] >> 22) & 1023], 1);
    __syncthreads();
    int t = threadIdx.x;
    int l0 = h[4*t], l1 = h[4*t+1], l2 = h[4*t+2], l3 = h[4*t+3];
    int lsum = l0 + l1 + l2 + l3;
    sarr[t] = lsum;
    __syncthreads();
    for (int off = 1; off < 256; off <<= 1) {
        int v = (t >= off) ? sarr[t - off] : 0;
        __syncthreads();
        sarr[t] += v;
        __syncthreads();
    }
    int excl = sarr[t] - lsum;
    base[4*t] = excl; base[4*t+1] = excl + l0;
    base[4*t+2] = excl + l0 + l1; base[4*t+3] = excl + l0 + l1 + l2;
    __syncthreads();
    int rowBase = c << COARSE_SHIFT;
    for (int i = threadIdx.x; i < 1024; i += 256) {
        int gr = rowBase + i;
        if (gr < N) rowStart[gr] = s + base[i];
    }
    if (threadIdx.x == 0 && c == Bc - 1) rowStart[N] = total;
    for (int i = threadIdx.x; i < 1024; i += 256) h[i] = 0;
    __syncthreads();
    for (int j = s + threadIdx.x; j < e; j += 256) {
        int k = stage[j];
        int r = (k >> 22) & 1023;
        int pos = s + base[r] + atomicAdd(&h[r], 1);
        bin[pos] = k;
        if (binVal) binVal[pos] = stageVal[j];
    }
}

// ---------------- gathers: QUARTER-WAVE rows + packed fp16 math ----------------
// One row per 16-lane quarter: lane owns 4 channels (= 1 HPack = 2 half2).
// Edge math: 2 x v_pk_fma_f16 per edge per lane, fp16 accumulators; mean /
// norm / residual in fp32. Keys 2-deep in registers, __shfl broadcast in
// wave-uniform control flow (trip count = wave-max of quarter caps).
// Lanes beyond deg hold key 0 (valid row 0); dead slots neutralized by
// zero-weight mask row (ent/node) or f=0 (user).

__global__ void __launch_bounds__(256)
ent_gather(const ushort* __restrict__ entCur,
           const float4* __restrict__ weight,
           const int* __restrict__ rowStart,
           const int* __restrict__ bin,
           ushort* __restrict__ entNewH,
           float* __restrict__ entOutF,          // non-null on final hop
           float* __restrict__ entNorm,
           int NE) {
    __shared__ HPack wlds[16 * 16];               // row 15 = zeros (mask row)
    for (int i = threadIdx.x; i < 15 * 16; i += blockDim.x) wlds[i] = f4hp(weight[i]);
    for (int i = threadIdx.x; i < 16; i += blockDim.x)
        wlds[15 * 16 + i] = f4hp(make_float4(0.f, 0.f, 0.f, 0.f));
    __syncthreads();
    int lane = threadIdx.x & 63;
    int l = lane & 15;
    int qbase = lane & 48;
    int row = blockIdx.x * 16 + ((threadIdx.x >> 6) << 2) + (lane >> 4);
    bool ok = row < NE;
    int start = 0, deg = 0;
    if (ok) { start = rowStart[row]; deg = rowStart[row + 1] - start; }
    int myk0 = (l < deg)      ? bin[start + l]      : 0;
    int myk1 = (16 + l < deg) ? bin[start + 16 + l] : 0;
    int cap = deg < 32 ? deg : 32;
    int capm = cap;
    capm = max(capm, __shfl_xor(capm, 16, 64));
    capm = max(capm, __shfl_xor(capm, 32, 64));
    int nb = (capm + 3) >> 2;
    __half2 aLo = __float2half2_rn(0.f), aHi = __float2half2_rn(0.f);
    for (int t = 0; t < nb; ++t) {
        int e0 = t << 2;
        int k0 = __shfl((e0     < 16) ? myk0 : myk1, qbase + ( e0      & 15), 64);
        int k1 = __shfl((e0 + 1 < 16) ? myk0 : myk1, qbase + ((e0 + 1) & 15), 64);
        int k2 = __shfl((e0 + 2 < 16) ? myk0 : myk1, qbase + ((e0 + 2) & 15), 64);
        int k3 = __shfl((e0 + 3 < 16) ? myk0 : myk1, qbase + ((e0 + 3) & 15), 64);
        HPack h0 = ((const HPack*)(entCur + (long)(k0 & 0x3FFFF) * CDIM))[l];
        HPack h1 = ((const HPack*)(entCur + (long)(k1 & 0x3FFFF) * CDIM))[l];
        HPack h2 = ((const HPack*)(entCur + (long)(k2 & 0x3FFFF) * CDIM))[l];
        HPack h3 = ((const HPack*)(entCur + (long)(k3 & 0x3FFFF) * CDIM))[l];
        int r0 = (e0     < cap) ? ((k0 >> 18) & 15) : 15;
        int r1 = (e0 + 1 < cap) ? ((k1 >> 18) & 15) : 15;
        int r2 = (e0 + 2 < cap) ? ((k2 >> 18) & 15) : 15;
        int r3 = (e0 + 3 < cap) ? ((k3 >> 18) & 15) : 15;
        HPack w0 = wlds[r0 * 16 + l];
        HPack w1 = wlds[r1 * 16 + l];
        HPack w2 = wlds[r2 * 16 + l];
        HPack w3 = wlds[r3 * 16 + l];
        aLo = __hfma2(h0.lo, w0.lo, aLo); aHi = __hfma2(h0.hi, w0.hi, aHi);
        aLo = __hfma2(h1.lo, w1.lo, aLo); aHi = __hfma2(h1.hi, w1.hi, aHi);
        aLo = __hfma2(h2.lo, w2.lo, aLo); aHi = __hfma2(h2.hi, w2.hi, aHi);
        aLo = __hfma2(h3.lo, w3.lo, aLo); aHi = __hfma2(h3.hi, w3.hi, aHi);
    }
    for (int e = 32; e < deg; ++e) {              // rare overflow, per-quarter
        int k = bin[start + e];
        HPack h = ((const HPack*)(entCur + (long)(k & 0x3FFFF) * CDIM))[l];
        HPack w = wlds[((k >> 18) & 15) * 16 + l];
        aLo = __hfma2(h.lo, w.lo, aLo); aHi = __hfma2(h.hi, w.hi, aHi);
    }
    float4 acc = hp2f4(aLo, aHi);
    float inv = 1.0f / fmaxf((float)deg, 1.0f);
    float4 mean = make_float4(acc.x * inv, acc.y * inv, acc.z * inv, acc.w * inv);
    float q2 = mean.x * mean.x + mean.y * mean.y + mean.z * mean.z + mean.w * mean.w;
    q2 += __shfl_xor(q2, 1, 64);
    q2 += __shfl_xor(q2, 2, 64);
    q2 += __shfl_xor(q2, 4, 64);
    q2 += __shfl_xor(q2, 8, 64);
    float n = fmaxf(sqrtf(q2), 1e-12f);
    float rn = 1.0f / n;
    if (ok) {
        float4 o = make_float4(mean.x * rn, mean.y * rn, mean.z * rn, mean.w * rn);
        ((ushort4*)(entNewH + (long)row * CDIM))[l] = f4h(o);
        if (entOutF) ((float4*)(entOutF + (long)row * CDIM))[l] = o;
        if (l == 0) entNorm[row] = n;
    }
}

// Unified fp16 node table [NN][CDIM] (user rows first): single base pointer.
__global__ void __launch_bounds__(256)
node_gather(const ushort* __restrict__ allCur,
            const float4* __restrict__ extraW,
            const int* __restrict__ rowStart,
            const int* __restrict__ bin,
            ushort* __restrict__ uNewH,          // null on final hop
            float* __restrict__ resOut,
            int NN, int NU) {
    __shared__ HPack wlds[17 * 16];               // row 16 = zeros (mask row)
    for (int i = threadIdx.x; i < 16 * 16; i += blockDim.x) wlds[i] = f4hp(extraW[i]);
    for (int i = threadIdx.x; i < 16; i += blockDim.x)
        wlds[16 * 16 + i] = f4hp(make_float4(0.f, 0.f, 0.f, 0.f));
    __syncthreads();
    int lane = threadIdx.x & 63;
    int l = lane & 15;
    int qbase = lane & 48;
    int row = blockIdx.x * 16 + ((threadIdx.x >> 6) << 2) + (lane >> 4);
    bool ok = row < NN;
    int start = 0, deg = 0;
    if (ok) { start = rowStart[row]; deg = rowStart[row + 1] - start; }
    int myk0 = (l < deg)      ? bin[start + l]      : 0;
    int myk1 = (16 + l < deg) ? bin[start + 16 + l] : 0;
    float4* resRow = (float4*)(resOut + (long)row * CDIM);
    float4 rvv = make_float4(0.f, 0.f, 0.f, 0.f);
    if (ok) rvv = resRow[l];                      // hoisted: overlaps gather loop
    int cap = deg < 32 ? deg : 32;
    int capm = cap;
    capm = max(capm, __shfl_xor(capm, 16, 64));
    capm = max(capm, __shfl_xor(capm, 32, 64));
    int nb = (capm + 3) >> 2;
    __half2 aLo = __float2half2_rn(0.f), aHi = __float2half2_rn(0.f);
    for (int t = 0; t < nb; ++t) {
        int e0 = t << 2;
        int k0 = __shfl((e0     < 16) ? myk0 : myk1, qbase + ( e0      & 15), 64);
        int k1 = __shfl((e0 + 1 < 16) ? myk0 : myk1, qbase + ((e0 + 1) & 15), 64);
        int k2 = __shfl((e0 + 2 < 16) ? myk0 : myk1, qbase + ((e0 + 2) & 15), 64);
        int k3 = __shfl((e0 + 3 < 16) ? myk0 : myk1, qbase + ((e0 + 3) & 15), 64);
        HPack h0 = ((const HPack*)(allCur + (long)(k0 & 0x3FFFF) * CDIM))[l];
        HPack h1 = ((const HPack*)(allCur + (long)(k1 & 0x3FFFF) * CDIM))[l];
        HPack h2 = ((const HPack*)(allCur + (long)(k2 & 0x3FFFF) * CDIM))[l];
        HPack h3 = ((const HPack*)(allCur + (long)(k3 & 0x3FFFF) * CDIM))[l];
        int r0 = (e0     < cap) ? ((k0 >> 18) & 15) : 16;
        int r1 = (e0 + 1 < cap) ? ((k1 >> 18) & 15) : 16;
        int r2 = (e0 + 2 < cap) ? ((k2 >> 18) & 15) : 16;
        int r3 = (e0 + 3 < cap) ? ((k3 >> 18) & 15) : 16;
        HPack w0 = wlds[r0 * 16 + l];
        HPack w1 = wlds[r1 * 16 + l];
        HPack w2 = wlds[r2 * 16 + l];
        HPack w3 = wlds[r3 * 16 + l];
        aLo = __hfma2(h0.lo, w0.lo, aLo); aHi = __hfma2(h0.hi, w0.hi, aHi);
        aLo = __hfma2(h1.lo, w1.lo, aLo); aHi = __hfma2(h1.hi, w1.hi, aHi);
        aLo = __hfma2(h2.lo, w2.lo, aLo); aHi = __hfma2(h2.hi, w2.hi, aHi);
        aLo = __hfma2(h3.lo, w3.lo, aLo); aHi = __hfma2(h3.hi, w3.hi, aHi);
    }
    for (int e = 32; e < deg; ++e) {
        int k = bin[start + e];
        HPack h = ((const HPack*)(allCur + (long)(k & 0x3FFFF) * CDIM))[l];
        HPack w = wlds[((k >> 18) & 15) * 16 + l];
        aLo = __hfma2(h.lo, w.lo, aLo); aHi = __hfma2(h.hi, w.hi, aHi);
    }
    float4 acc = hp2f4(aLo, aHi);
    float inv = 1.0f / fmaxf((float)deg, 1.0f);
    float4 mean = make_float4(acc.x * inv, acc.y * inv, acc.z * inv, acc.w * inv);
    float q2 = mean.x * mean.x + mean.y * mean.y + mean.z * mean.z + mean.w * mean.w;
    q2 += __shfl_xor(q2, 1, 64);
    q2 += __shfl_xor(q2, 2, 64);
    q2 += __shfl_xor(q2, 4, 64);
    q2 += __shfl_xor(q2, 8, 64);
    float rn = 1.0f / fmaxf(sqrtf(q2), 1e-12f);
    if (ok) {
        float4 o = make_float4(mean.x * rn, mean.y * rn, mean.z * rn, mean.w * rn);
        resRow[l] = make_float4(rvv.x + o.x, rvv.y + o.y, rvv.z + o.z, rvv.w + o.w);
        if (row < NU && uNewH) ((ushort4*)(uNewH + (long)row * CDIM))[l] = f4h(o);
    }
}

__global__ void __launch_bounds__(256)
user_gather(const ushort* __restrict__ entNewH,
            const float* __restrict__ entNorm,
            const int* __restrict__ rowStart,
            const int* __restrict__ bin,
            const float* __restrict__ binVal,
            float* __restrict__ userRes,
            int NU) {
    int lane = threadIdx.x & 63;
    int l = lane & 15;
    int qbase = lane & 48;
    int row = blockIdx.x * 16 + ((threadIdx.x >> 6) << 2) + (lane >> 4);
    bool ok = row < NU;
    int start = 0, deg = 0;
    if (ok) { start = rowStart[row]; deg = rowStart[row + 1] - start; }
    int myk0 = 0, myk1 = 0; float myv0 = 0.f, myv1 = 0.f;
    if (l < deg)      { myk0 = bin[start + l];      myv0 = binVal[start + l]; }
    if (16 + l < deg) { myk1 = bin[start + 16 + l]; myv1 = binVal[start + 16 + l]; }
    float4* resRow = (float4*)(userRes + (long)row * CDIM);
    float4 rvv = make_float4(0.f, 0.f, 0.f, 0.f);
    if (ok) rvv = resRow[l];
    int cap = deg < 32 ? deg : 32;
    int capm = cap;
    capm = max(capm, __shfl_xor(capm, 16, 64));
    capm = max(capm, __shfl_xor(capm, 32, 64));
    int nb = (capm + 3) >> 2;
    __half2 aLo = __float2half2_rn(0.f), aHi = __float2half2_rn(0.f);
    for (int t = 0; t < nb; ++t) {
        int e0 = t << 2;
        int k0 = __shfl((e0     < 16) ? myk0 : myk1, qbase + ( e0      & 15), 64);
        int k1 = __shfl((e0 + 1 < 16) ? myk0 : myk1, qbase + ((e0 + 1) & 15), 64);
        int k2 = __shfl((e0 + 2 < 16) ? myk0 : myk1, qbase + ((e0 + 2) & 15), 64);
        int k3 = __shfl((e0 + 3 < 16) ? myk0 : myk1, qbase + ((e0 + 3) & 15), 64);
        float a0 = __shfl((e0     < 16) ? myv0 : myv1, qbase + ( e0      & 15), 64);
        float a1 = __shfl((e0 + 1 < 16) ? myv0 : myv1, qbase + ((e0 + 1) & 15), 64);
        float a2 = __shfl((e0 + 2 < 16) ? myv0 : myv1, qbase + ((e0 + 2) & 15), 64);
        float a3 = __shfl((e0 + 3 < 16) ? myv0 : myv1, qbase + ((e0 + 3) & 15), 64);
        int c0 = k0 & 0x3FFFFF, c1 = k1 & 0x3FFFFF;
        int c2 = k2 & 0x3FFFFF, c3 = k3 & 0x3FFFFF;
        float f0 = (e0     < cap) ? entNorm[c0] * a0 : 0.f;
        float f1 = (e0 + 1 < cap) ? entNorm[c1] * a1 : 0.f;
        float f2 = (e0 + 2 < cap) ? entNorm[c2] * a2 : 0.f;
        float f3 = (e0 + 3 < cap) ? entNorm[c3] * a3 : 0.f;
        HPack h0 = ((const HPack*)(entNewH + (long)c0 * CDIM))[l];
        HPack h1 = ((const HPack*)(entNewH + (long)c1 * CDIM))[l];
        HPack h2 = ((const HPack*)(entNewH + (long)c2 * CDIM))[l];
        HPack h3 = ((const HPack*)(entNewH + (long)c3 * CDIM))[l];
        __half2 g0 = __float2half2_rn(f0);
        __half2 g1 = __float2half2_rn(f1);
        __half2 g2 = __float2half2_rn(f2);
        __half2 g3 = __float2half2_rn(f3);
        aLo = __hfma2(h0.lo, g0, aLo); aHi = __hfma2(h0.hi, g0, aHi);
        aLo = __hfma2(h1.lo, g1, aLo); aHi = __hfma2(h1.hi, g1, aHi);
        aLo = __hfma2(h2.lo, g2, aLo); aHi = __hfma2(h2.hi, g2, aHi);
        aLo = __hfma2(h3.lo, g3, aLo); aHi = __hfma2(h3.hi, g3, aHi);
    }
    for (int e = 32; e < deg; ++e) {
        int k = bin[start + e];
        float a = binVal[start + e];
        int c = k & 0x3FFFFF;
        __half2 g = __float2half2_rn(entNorm[c] * a);
        HPack h = ((const HPack*)(entNewH + (long)c * CDIM))[l];
        aLo = __hfma2(h.lo, g, aLo); aHi = __hfma2(h.hi, g, aHi);
    }
    float4 acc = hp2f4(aLo, aHi);
    float q2 = acc.x * acc.x + acc.y * acc.y + acc.z * acc.z + acc.w * acc.w;
    q2 += __shfl_xor(q2, 1, 64);
    q2 += __shfl_xor(q2, 2, 64);
    q2 += __shfl_xor(q2, 4, 64);
    q2 += __shfl_xor(q2, 8, 64);
    float rn = 1.0f / fmaxf(sqrtf(q2), 1e-12f);
    if (ok) {
        resRow[l] = make_float4(rvv.x + acc.x * rn, rvv.y + acc.y * rn,
                                rvv.z + acc.z * rn, rvv.w + acc.w * rn);
    }
}

__global__ void fill_debug(float* __restrict__ out, long n, float val) {
    long i = (long)blockIdx.x * blockDim.x + threadIdx.x;
    if (i < n) out[i] = val;
}

extern "C" void kernel_launch(void* const* d_in, const int* in_sizes, int n_in,
                              void* d_out, int out_size, void* d_ws, size_t ws_size,
                              hipStream_t stream) {
    const float* user_emb = (const float*)d_in[0];
    const float* ent_emb  = (const float*)d_in[1];
    const float* weight   = (const float*)d_in[2];
    const float* extraW   = (const float*)d_in[3];
    const float* imVal    = (const float*)d_in[4];
    const int*   eidx     = (const int*)d_in[5];
    const int*   etype    = (const int*)d_in[6];
    const int*   xidx     = (const int*)d_in[7];
    const int*   xtype    = (const int*)d_in[8];
    const int*   imRow    = (const int*)d_in[9];
    const int*   imCol    = (const int*)d_in[10];

    const int NU  = in_sizes[0] / CDIM;
    const int NE  = in_sizes[1] / CDIM;
    const int NN  = NU + NE;
    const int E   = in_sizes[5] / 2;
    const int E2  = in_sizes[7] / 2;
    const int NNZ = in_sizes[4];
    const long nuC = (long)NU * CDIM, neC = (long)NE * CDIM, nnC = (long)NN * CDIM;

    const int BcE = (NE + 1023) >> 10, BcN = (NN + 1023) >> 10, BcU = (NU + 1023) >> 10;

    float* out = (float*)d_out;
    float* outUserRes = out;            // [0 : nuC]
    float* entOut     = out + nuC;      // [nuC : nnC] final-hop entity (fp32)
    float* outNodeRes = out + nnC;      // [nnC : 2nnC]

    // ---- workspace layout ----
    size_t commonBytes = (size_t)NE * 4                    // entNorm
                       + (size_t)(E + E2 + NNZ) * 4 * 2    // stage + bin keys
                       + (size_t)NNZ * 4 * 2               // stageVal + binVal
                       + (size_t)(3 * MAXB) * 4            // coarse counts
                       + (size_t)(3 * (MAXB + 1)) * 4      // coarse starts
                       + (size_t)(3 * MAXB) * 4            // cursors
                       + (size_t)(NE + NN + NU + 3) * 4;   // rowStart CSR arrays
    size_t halfBytes = (size_t)nnC * 2 * 2;                // 2x unified fp16 node table
    size_t required = commonBytes + 256 + halfBytes;
    if (ws_size < required) {
        long total = 2 * nnC;
        fill_debug<<<(total + 255) / 256, 256, 0, stream>>>(out, total, (float)(ws_size >> 20));
        return;
    }

    char* w = (char*)d_ws;
    float* entNorm  = (float*)w; w += (size_t)NE * 4;
    int* stageEnt   = (int*)w;   w += (size_t)E * 4;
    int* stageNode  = (int*)w;   w += (size_t)E2 * 4;
    int* stageU     = (int*)w;   w += (size_t)NNZ * 4;
    float* stageUv  = (float*)w; w += (size_t)NNZ * 4;
    int* binEnt     = (int*)w;   w += (size_t)E * 4;
    int* binNode    = (int*)w;   w += (size_t)E2 * 4;
    int* binU       = (int*)w;   w += (size_t)NNZ * 4;
    float* binUv    = (float*)w; w += (size_t)NNZ * 4;
    int* cntC       = (int*)w;   w += (size_t)(3 * MAXB) * 4;
    int* startE     = (int*)w;   w += (size_t)(MAXB + 1) * 4;
    int* startN     = (int*)w;   w += (size_t)(MAXB + 1) * 4;
    int* startU     = (int*)w;   w += (size_t)(MAXB + 1) * 4;
    int* curE       = (int*)w;   w += (size_t)MAXB * 4;
    int* curN       = (int*)w;   w += (size_t)MAXB * 4;
    int* curU       = (int*)w;   w += (size_t)MAXB * 4;
    int* rowSE      = (int*)w;   w += (size_t)(NE + 1) * 4;
    int* rowSN      = (int*)w;   w += (size_t)(NN + 1) * 4;
    int* rowSU      = (int*)w;   w += (size_t)(NU + 1) * 4;
    w = (char*)(((uintptr_t)w + 255) & ~(uintptr_t)255);   // align fp16 tables
    ushort* allH_A  = (ushort*)w; w += (size_t)nnC * 2;    // [user | entity] fp16
    ushort* allH_B  = (ushort*)w; w += (size_t)nnC * 2;

    const size_t entOff = (size_t)NU * CDIM;               // entity half offset

    const int* head = eidx;  const int* tail = eidx + E;
    const int* eh   = xidx;  const int* et   = xidx + E2;

    hipMemsetAsync(cntC, 0, (size_t)(3 * MAXB) * 4, stream);

    long initN4 = (nuC > neC ? nuC : neC) / 4;
    init_kernel<<<(initN4 + 255) / 256, 256, 0, stream>>>(
        (const float4*)user_emb, (const float4*)ent_emb,
        (float4*)outUserRes, (float4*)outNodeRes,
        (ushort4*)allH_A, (ushort4*)(allH_A + entOff), nuC / 4, neC / 4);

    // ---- build: hist -> scan -> coarse bin -> per-row subsort (CSR) ----
    hist_coarse<<<256, 256, 0, stream>>>(head,  E,   cntC,            BcE);
    hist_coarse<<<256, 256, 0, stream>>>(eh,    E2,  cntC + MAXB,     BcN);
    hist_coarse<<<256, 256, 0, stream>>>(imRow, NNZ, cntC + 2 * MAXB, BcU);

    scan_small<<<1, 256, 0, stream>>>(cntC,            startE, curE, BcE);
    scan_small<<<1, 256, 0, stream>>>(cntC + MAXB,     startN, curN, BcN);
    scan_small<<<1, 256, 0, stream>>>(cntC + 2 * MAXB, startU, curU, BcU);

    bin_pairs<<<(E  + CHUNK - 1) / CHUNK, 256, 0, stream>>>(head, tail, etype, -1, E,  curE, stageEnt);
    bin_pairs<<<(E2 + CHUNK - 1) / CHUNK, 256, 0, stream>>>(eh,   et,   xtype,  0, E2, curN, stageNode);
    bin_user <<<(NNZ + CHUNK - 1) / CHUNK, 256, 0, stream>>>(imRow, imCol, imVal, NNZ, curU, stageU, stageUv);

    subsort<<<BcE, 256, 0, stream>>>(startE, stageEnt,  nullptr, binEnt,  nullptr, rowSE, BcE, NE, E);
    subsort<<<BcN, 256, 0, stream>>>(startN, stageNode, nullptr, binNode, nullptr, rowSN, BcN, NN, E2);
    subsort<<<BcU, 256, 0, stream>>>(startU, stageU,    stageUv, binU,    binUv,   rowSU, BcU, NU, NNZ);

    // ---- 3 hops (unified fp16 node table, quarter-wave packed-fp16 gathers) ----
    ushort* allCur  = allH_A;
    ushort* allNext = allH_B;

    for (int hop = 0; hop < 3; ++hop) {
        ent_gather<<<(NE + 15) / 16, 256, 0, stream>>>(
            allCur + entOff, (const float4*)weight, rowSE, binEnt,
            allNext + entOff, (hop == 2) ? entOut : nullptr, entNorm, NE);
        node_gather<<<(NN + 15) / 16, 256, 0, stream>>>(
            allCur, (const float4*)extraW, rowSN, binNode,
            (hop == 2) ? nullptr : allNext, outNodeRes, NN, NU);
        user_gather<<<(NU + 15) / 16, 256, 0, stream>>>(
            allNext + entOff, entNorm, rowSU, binU, binUv, outUserRes, NU);

        ushort* t = allCur; allCur = allNext; allNext = t;
    }
}